// Round 11
// baseline (542.239 us; speedup 1.0000x reference)
//
#include <hip/hip_runtime.h>

// 3-NN IDW upsampling, round 11: Gaussian-CDF-warped grid (equal-mass cells),
// lane-owned queries with dual med3 chains (ILP), capped wave boxes + block
// pass-2 queue for stragglers. Exact f64 re-rank + f64 IDW epilogue
// (identical arithmetic to all passing rounds; absmax 0.00390625).
// Correctness does NOT depend on the warp constants (any monotone grid is
// exact); they only balance work.

constexpr int   B  = 2;
constexpr int   S  = 4096;
constexpr int   NQ = 16384;
constexpr int   G  = 16;
constexpr int   NC = G * G * G;
constexpr unsigned NOKEY = 0xFFFFFFFFu;

constexpr int THREADS = 512;            // 8 waves
constexpr int PPT     = S / THREADS;    // 8 build points per thread
constexpr int QPB     = 512;            // queries per block (1 per lane)
constexpr int CAP     = 5;              // max wave-box span per axis

__constant__ float TH[15] = {           // Phi^-1(k/16), k=1..15
    -1.53412054f, -1.15034938f, -0.88714656f, -0.67448975f, -0.48877641f,
    -0.31863936f, -0.15731068f,  0.00000000f,  0.15731068f,  0.31863936f,
     0.48877641f,  0.67448975f,  0.88714656f,  1.15034938f,  1.53412054f };
__constant__ float BND[17] = {          // cell c spans [BND[c], BND[c+1]]
    -1e30f,
    -1.53412054f, -1.15034938f, -0.88714656f, -0.67448975f, -0.48877641f,
    -0.31863936f, -0.15731068f,  0.00000000f,  0.15731068f,  0.31863936f,
     0.48877641f,  0.67448975f,  0.88714656f,  1.15034938f,  1.53412054f,
     1e30f };

__device__ __forceinline__ unsigned med3u(unsigned a, unsigned b, unsigned c) {
    unsigned d;
    asm("v_med3_u32 %0, %1, %2, %3" : "=v"(d) : "v"(a), "v"(b), "v"(c));
    return d;
}
__device__ __forceinline__ int cell1w(float v) {   // warped cell: count thresholds below
    int c = 0;
    #pragma unroll
    for (int k = 0; k < 15; ++k) c += (v > TH[k]) ? 1 : 0;
    return c;
}
__device__ __forceinline__ unsigned spread3(unsigned v) {
    return (v & 1u) | ((v & 2u) << 2) | ((v & 4u) << 4) | ((v & 8u) << 6);
}

// ---------------- Morton-sort query indices (proven r8 kernel, warped cells)
__global__ __launch_bounds__(1024)
void k_qsort(const float* __restrict__ xyz, unsigned* __restrict__ dsrt)
{
    __shared__ unsigned pk[2048];
    __shared__ unsigned wsum[16];
    const int b = blockIdx.x;
    const int t = threadIdx.x;
    const float* xb = xyz + (size_t)b * 3 * NQ;

    pk[t] = 0u; pk[t + 1024] = 0u;
    __syncthreads();

    unsigned short mc[16];
    #pragma unroll
    for (int k = 0; k < 16; ++k) {
        const int q = k * 1024 + t;
        const int hx = cell1w(xb[q]), hy = cell1w(xb[NQ + q]), hz = cell1w(xb[2 * NQ + q]);
        const unsigned m = spread3(hx) | (spread3(hy) << 1) | (spread3(hz) << 2);
        mc[k] = (unsigned short)m;
        atomicAdd(&pk[m >> 1], (m & 1) ? 0x10000u : 1u);
    }
    __syncthreads();

    {
        const unsigned w0 = pk[2 * t], w1 = pk[2 * t + 1];
        const unsigned c0 = w0 & 0xFFFFu, c1 = w0 >> 16;
        const unsigned c2 = w1 & 0xFFFFu, c3 = w1 >> 16;
        const unsigned tsum = c0 + c1 + c2 + c3;
        const int lane = t & 63, w = t >> 6;
        unsigned sc = tsum;
        #pragma unroll
        for (int d = 1; d < 64; d <<= 1) {
            const unsigned o = __shfl_up(sc, d, 64);
            if (lane >= d) sc += o;
        }
        if (lane == 63) wsum[w] = sc;
        __syncthreads();
        unsigned wbase = 0;
        #pragma unroll
        for (int k = 0; k < 16; ++k) wbase += (k < w) ? wsum[k] : 0u;
        unsigned e = wbase + sc - tsum;
        const unsigned e0 = e; e += c0;
        const unsigned e1 = e; e += c1;
        const unsigned e2 = e; e += c2;
        const unsigned e3 = e;
        __syncthreads();
        pk[2 * t]     = e0 | (e1 << 16);
        pk[2 * t + 1] = e2 | (e3 << 16);
    }
    __syncthreads();

    #pragma unroll
    for (int k = 0; k < 16; ++k) {
        const int q = k * 1024 + t;
        const unsigned m = mc[k];
        const unsigned old = atomicAdd(&pk[m >> 1], (m & 1) ? 0x10000u : 1u);
        const unsigned pos = (m & 1) ? (old >> 16) : (old & 0xFFFFu);
        dsrt[b * NQ + pos] = (unsigned)q;
    }
}

// ---------------- main kernel ---------------------------------------------
__global__ __launch_bounds__(THREADS)
void k_knn(const float* __restrict__ xyz, const float* __restrict__ sxyz,
           const float* __restrict__ sflow, float* __restrict__ out,
           const unsigned* __restrict__ dsrt)
{
    __shared__ float4 pq[S];                 // 64 KiB: cell-sorted (x,y,z,origidx)
    __shared__ unsigned short pfx16[NC + 2]; // cell prefix table
    __shared__ unsigned scratch[NC / 2];     // build: packed u16 cnt/cursors
    __shared__ unsigned wtot[8];
    __shared__ unsigned q2buf[QPB];
    __shared__ unsigned q2n;

    const int t    = threadIdx.x;
    const int lane = t & 63;
    const int wv   = t >> 6;
    const int blk  = blockIdx.x;             // 0..63
    const int b    = blk >> 5;
    const int chk  = blk & 31;

    if (t == 0) q2n = 0u;

    // ========== build warped grid in LDS ===================================
    const float* sxb = sxyz + (size_t)b * 3 * S;
    float xx[PPT], yy[PPT], zz[PPT]; int cc[PPT];
    {
        const float4* vx = reinterpret_cast<const float4*>(sxb + t * PPT);
        const float4* vy = reinterpret_cast<const float4*>(sxb + S + t * PPT);
        const float4* vz = reinterpret_cast<const float4*>(sxb + 2 * S + t * PPT);
        #pragma unroll
        for (int k = 0; k < PPT / 4; ++k) {
            const float4 a = vx[k], c = vy[k], d = vz[k];
            xx[4*k+0]=a.x; xx[4*k+1]=a.y; xx[4*k+2]=a.z; xx[4*k+3]=a.w;
            yy[4*k+0]=c.x; yy[4*k+1]=c.y; yy[4*k+2]=c.z; yy[4*k+3]=c.w;
            zz[4*k+0]=d.x; zz[4*k+1]=d.y; zz[4*k+2]=d.z; zz[4*k+3]=d.w;
        }
    }
    #pragma unroll
    for (int k = 0; k < 4; ++k) scratch[t * 4 + k] = 0u;
    __syncthreads();

    #pragma unroll
    for (int k = 0; k < PPT; ++k) {
        cc[k] = (cell1w(zz[k]) * G + cell1w(yy[k])) * G + cell1w(xx[k]);
        atomicAdd(&scratch[cc[k] >> 1], (cc[k] & 1) ? 0x10000u : 1u);
    }
    __syncthreads();

    {   // exclusive scan of 4096 u16 counts (thread t owns cells 8t..8t+7)
        unsigned c[8];
        #pragma unroll
        for (int k = 0; k < 4; ++k) {
            const unsigned w2 = scratch[t * 4 + k];
            c[2*k] = w2 & 0xFFFFu; c[2*k+1] = w2 >> 16;
        }
        unsigned tsum = 0;
        #pragma unroll
        for (int k = 0; k < 8; ++k) { const unsigned v = c[k]; c[k] = tsum; tsum += v; }
        unsigned sc = tsum;
        #pragma unroll
        for (int d = 1; d < 64; d <<= 1) {
            const unsigned o = __shfl_up(sc, d, 64);
            if (lane >= d) sc += o;
        }
        if (lane == 63) wtot[wv] = sc;
        __syncthreads();
        unsigned wbase = 0;
        #pragma unroll
        for (int k = 0; k < 8; ++k) wbase += (k < wv) ? wtot[k] : 0u;
        const unsigned base = wbase + sc - tsum;
        #pragma unroll
        for (int k = 0; k < 8; ++k) pfx16[t * 8 + k] = (unsigned short)(base + c[k]);
        #pragma unroll
        for (int k = 0; k < 4; ++k)
            scratch[t * 4 + k] = (base + c[2*k]) | ((base + c[2*k+1]) << 16);
        if (t == 0) pfx16[NC] = (unsigned short)S;
    }
    __syncthreads();

    #pragma unroll
    for (int k = 0; k < PPT; ++k) {
        const int ci = cc[k];
        const unsigned old = atomicAdd(&scratch[ci >> 1], (ci & 1) ? 0x10000u : 1u);
        const unsigned pos = (ci & 1) ? (old >> 16) : (old & 0xFFFFu);
        pq[pos] = make_float4(xx[k], yy[k], zz[k],
                              __uint_as_float((unsigned)(t * PPT + k)));
    }
    __syncthreads();

    auto ins5 = [] __device__ (unsigned& k0, unsigned& k1, unsigned& k2,
                               unsigned& k3, unsigned& k4, unsigned c) {
        k4 = med3u(k3, k4, c); k3 = med3u(k2, k3, c); k2 = med3u(k1, k2, c);
        k1 = med3u(k0, k1, c); k0 = min(k0, c);
    };

    const float* xb = xyz + (size_t)b * 3 * NQ;
    const float* fb = sflow + (size_t)b * 3 * S;
    float*       ob = out   + (size_t)b * 3 * NQ;

    // f64 epilogue: exact re-rank of 5 keys + IDW (same arithmetic as r1-r10)
    auto epilogue = [&] __device__ (unsigned qq, float qxf, float qyf, float qzf,
                                    unsigned m0, unsigned m1, unsigned m2,
                                    unsigned m3, unsigned m4) {
        const unsigned bkarr[5] = { m0, m1, m2, m3, m4 };
        const double qxd = (double)qxf, qyd = (double)qyf, qzd = (double)qzf;
        double e0 = 1e300, e1 = 1e300, e2 = 1e300;
        int    i0 = 0,     i1 = 0,     i2 = 0;
        #pragma unroll
        for (int c = 0; c < 5; ++c) {
            const unsigned key = bkarr[c];
            if (key == NOKEY) continue;
            const int j = (int)(key & 0xFFFu);
            const float4 p = pq[j];
            const double dx = qxd - (double)p.x;
            const double dy = qyd - (double)p.y;
            const double dz = qzd - (double)p.z;
            const double d2 = dx * dx + dy * dy + dz * dz;
            if (d2 < e2) {
                if (d2 < e1) {
                    e2 = e1; i2 = i1;
                    if (d2 < e0) { e1 = e0; i1 = i0; e0 = d2; i0 = j; }
                    else         { e1 = d2; i1 = j; }
                } else {
                    e2 = d2; i2 = j;
                }
            }
        }
        double dist0 = sqrt(e0); dist0 = dist0 > 1e-10 ? dist0 : 1e-10;
        double dist1 = sqrt(e1); dist1 = dist1 > 1e-10 ? dist1 : 1e-10;
        double dist2 = sqrt(e2); dist2 = dist2 > 1e-10 ? dist2 : 1e-10;
        const double inv0 = 1.0 / dist0, inv1 = 1.0 / dist1, inv2 = 1.0 / dist2;
        const double wsum = inv0 + inv1 + inv2;
        const unsigned so0 = __float_as_uint(pq[i0].w);
        const unsigned so1 = __float_as_uint(pq[i1].w);
        const unsigned so2 = __float_as_uint(pq[i2].w);
        #pragma unroll
        for (int c = 0; c < 3; ++c) {
            const float* fc = fb + c * S;
            const double o =
                (inv0 * (double)fc[so0] +
                 inv1 * (double)fc[so1] +
                 inv2 * (double)fc[so2]) / wsum;
            ob[c * NQ + qq] = (float)o;
        }
    };

    // ========== pass 1: lane-owned queries, capped wave box ================
    const int qslot = chk * QPB + wv * 64 + lane;
    const unsigned qi = dsrt[b * NQ + qslot];
    const float qx = xb[qi], qy = xb[NQ + qi], qz = xb[2 * NQ + qi];
    const int hx = cell1w(qx), hy = cell1w(qy), hz = cell1w(qz);

    int bx0 = hx, bx1 = hx, by0 = hy, by1 = hy, bz0 = hz, bz1 = hz;
    #pragma unroll
    for (int d = 1; d < 64; d <<= 1) {
        bx0 = min(bx0, __shfl_xor(bx0, d, 64)); bx1 = max(bx1, __shfl_xor(bx1, d, 64));
        by0 = min(by0, __shfl_xor(by0, d, 64)); by1 = max(by1, __shfl_xor(by1, d, 64));
        bz0 = min(bz0, __shfl_xor(bz0, d, 64)); bz1 = max(bz1, __shfl_xor(bz1, d, 64));
    }
    if (bx1 - bx0 > CAP) { const int m = (bx0 + bx1) >> 1; bx0 = max(m - CAP/2, 0); bx1 = min(bx0 + CAP, G-1); }
    if (by1 - by0 > CAP) { const int m = (by0 + by1) >> 1; by0 = max(m - CAP/2, 0); by1 = min(by0 + CAP, G-1); }
    if (bz1 - bz0 > CAP) { const int m = (bz0 + bz1) >> 1; bz0 = max(m - CAP/2, 0); bz1 = min(bz0 + CAP, G-1); }

    const int X0 = max(bx0 - 1, 0), X1 = min(bx1 + 1, G - 1);
    const int Y0 = max(by0 - 1, 0), Y1 = min(by1 + 1, G - 1);
    const int Z0 = max(bz0 - 1, 0), Z1 = min(bz1 + 1, G - 1);
    const int nyw   = Y1 - Y0 + 1;
    const int nrows = (Z1 - Z0 + 1) * nyw;       // <= 49 < 64

    unsigned ss = 0, se = 0;
    if (lane < nrows) {                           // parallel row-bounds fetch
        const int z = Z0 + lane / nyw, y = Y0 + lane % nyw;
        const int rb = (z * G + y) * G;
        ss = pfx16[rb + X0];
        se = pfx16[rb + X1 + 1];
    }

    unsigned a0=NOKEY,a1=NOKEY,a2=NOKEY,a3=NOKEY,a4=NOKEY;   // chain A
    unsigned c0=NOKEY,c1=NOKEY,c2=NOKEY,c3=NOKEY,c4=NOKEY;   // chain B

    for (int ri = 0; ri < nrows; ++ri) {
        const unsigned s0 = (unsigned)__shfl((int)ss, ri, 64);
        const unsigned e0 = (unsigned)__shfl((int)se, ri, 64);
        for (unsigned j = s0; j < e0; j += 2) {
            {
                const float4 p = pq[j];
                const float dxq = qx - p.x, dyq = qy - p.y, dzq = qz - p.z;
                const float d2 = dxq*dxq + dyq*dyq + dzq*dzq;
                ins5(a0,a1,a2,a3,a4, (__float_as_uint(d2) & 0xFFFFF000u) | j);
            }
            if (j + 1 < e0) {
                const float4 p = pq[j + 1];
                const float dxq = qx - p.x, dyq = qy - p.y, dzq = qz - p.z;
                const float d2 = dxq*dxq + dyq*dyq + dzq*dzq;
                ins5(c0,c1,c2,c3,c4, (__float_as_uint(d2) & 0xFFFFF000u) | (j+1));
            }
        }
    }
    // merge chain B into A -> exact top-5 of scanned set
    ins5(a0,a1,a2,a3,a4, c0); ins5(a0,a1,a2,a3,a4, c1); ins5(a0,a1,a2,a3,a4, c2);
    ins5(a0,a1,a2,a3,a4, c3); ins5(a0,a1,a2,a3,a4, c4);

    bool done = false;
    if (a2 != NOKEY) {
        const float h = sqrtf(__uint_as_float(a2 | 0xFFFu) * 1.0002f) * 1.0001f + 1e-7f;
        done = (X0 == 0     || qx - h >= BND[X0])     && (X1 == G-1 || qx + h <= BND[X1+1])
            && (Y0 == 0     || qy - h >= BND[Y0])     && (Y1 == G-1 || qy + h <= BND[Y1+1])
            && (Z0 == 0     || qz - h >= BND[Z0])     && (Z1 == G-1 || qz + h <= BND[Z1+1]);
    }
    if (done) {
        epilogue(qi, qx, qy, qz, a0, a1, a2, a3, a4);
    } else {
        const unsigned slot = atomicAdd(&q2n, 1u);
        q2buf[slot] = qi;
    }
    __syncthreads();

    // ========== pass 2: one full wave per straggler query ==================
    const int n2 = (int)q2n;
    for (int e2i = wv; e2i < n2; e2i += 8) {
        const unsigned qj = q2buf[e2i];
        const float q2x = xb[qj], q2y = xb[NQ + qj], q2z = xb[2 * NQ + qj];
        const int h2x = cell1w(q2x), h2y = cell1w(q2y), h2z = cell1w(q2z);

        unsigned m0, m1, m2, m3, m4;
        for (int r = 1; ; ++r) {
            const int rX0 = max(h2x - r, 0), rX1 = min(h2x + r, G - 1);
            const int rY0 = max(h2y - r, 0), rY1 = min(h2y + r, G - 1);
            const int rZ0 = max(h2z - r, 0), rZ1 = min(h2z + r, G - 1);
            m0 = m1 = m2 = m3 = m4 = NOKEY;
            const int ny2 = rY1 - rY0 + 1;
            const int nr2 = (rZ1 - rZ0 + 1) * ny2;
            for (int rb2 = 0; rb2 < nr2; rb2 += 64) {
                unsigned ts = 0, te = 0;
                const int ri = rb2 + lane;
                if (ri < nr2) {
                    const int z = rZ0 + ri / ny2, y = rY0 + ri % ny2;
                    const int rw = (z * G + y) * G;
                    ts = pfx16[rw + rX0];
                    te = pfx16[rw + rX1 + 1];
                }
                const int lim = min(64, nr2 - rb2);
                for (int k = 0; k < lim; ++k) {
                    const unsigned s0 = (unsigned)__shfl((int)ts, k, 64);
                    const unsigned e0 = (unsigned)__shfl((int)te, k, 64);
                    for (unsigned j = s0 + lane; j < e0; j += 64) {
                        const float4 p = pq[j];
                        const float dxq = q2x - p.x, dyq = q2y - p.y, dzq = q2z - p.z;
                        const float d2 = dxq*dxq + dyq*dyq + dzq*dzq;
                        ins5(m0,m1,m2,m3,m4, (__float_as_uint(d2) & 0xFFFFF000u) | j);
                    }
                }
            }
            // butterfly merge: all lanes converge to the same top-5
            #pragma unroll
            for (int d = 1; d < 64; d <<= 1) {
                const unsigned p0 = (unsigned)__shfl_xor((int)m0, d, 64);
                const unsigned p1 = (unsigned)__shfl_xor((int)m1, d, 64);
                const unsigned p2 = (unsigned)__shfl_xor((int)m2, d, 64);
                const unsigned p3 = (unsigned)__shfl_xor((int)m3, d, 64);
                const unsigned p4 = (unsigned)__shfl_xor((int)m4, d, 64);
                ins5(m0,m1,m2,m3,m4, p0); ins5(m0,m1,m2,m3,m4, p1);
                ins5(m0,m1,m2,m3,m4, p2); ins5(m0,m1,m2,m3,m4, p3);
                ins5(m0,m1,m2,m3,m4, p4);
            }
            const bool full = (rX0 == 0 && rX1 == G-1 && rY0 == 0 && rY1 == G-1 &&
                               rZ0 == 0 && rZ1 == G-1);
            bool ok = false;
            if (m2 != NOKEY) {
                const float h = sqrtf(__uint_as_float(m2 | 0xFFFu) * 1.0002f) * 1.0001f + 1e-7f;
                ok = (rX0 == 0   || q2x - h >= BND[rX0])   && (rX1 == G-1 || q2x + h <= BND[rX1+1])
                  && (rY0 == 0   || q2y - h >= BND[rY0])   && (rY1 == G-1 || q2y + h <= BND[rY1+1])
                  && (rZ0 == 0   || q2z - h >= BND[rZ0])   && (rZ1 == G-1 || q2z + h <= BND[rZ1+1]);
            }
            if (ok || full) break;
        }
        if (lane == 0)
            epilogue(qj, q2x, q2y, q2z, m0, m1, m2, m3, m4);
    }
}

extern "C" void kernel_launch(void* const* d_in, const int* in_sizes, int n_in,
                              void* d_out, int out_size, void* d_ws, size_t ws_size,
                              hipStream_t stream)
{
    const float* xyz  = (const float*)d_in[0];
    const float* sxyz = (const float*)d_in[1];
    const float* sflw = (const float*)d_in[2];
    float*       out  = (float*)d_out;
    unsigned*    dsrt = (unsigned*)d_ws;        // u32[2][16384] = 128 KB

    k_qsort<<<B, 1024, 0, stream>>>(xyz, dsrt);

    const int blocks = (B * NQ) / QPB;          // 64 blocks x 512 thr
    k_knn<<<blocks, THREADS, 0, stream>>>(xyz, sxyz, sflw, out, dsrt);
}

// Round 12
// 39.522 us; speedup vs baseline: 13.7200x; 13.7200x over previous
//
#include <hip/hip_runtime.h>

// 3-NN IDW upsampling, round 12: back to the proven round-4 brute-force
// structure (best measured: 44.2 us, 68% VALUBusy) with issue-side fixes:
//  - 512-thread blocks, __launch_bounds__(512,4), grid 512 = exactly 2
//    blocks/CU -> 16 waves/CU (vs r4's ~10) for latency hiding.
//  - AoS float4 {x,y,z,|p|^2} in LDS: ONE ds_read_b128 per point, and
//    dot-form distance v2 = (qq+1e-3) - 2 q.p + pp = 3 FMA + 1 add
//    (vs 6 ops diff-form). Bias 1e-3 >> fp32 error keeps keys positive;
//    key truncation noise unchanged vs r4.
//  - Merge + exact-f64 re-rank + f64 IDW epilogue verbatim from round 4
//    (passed, absmax 0.00390625). No index permutation (no sort).

constexpr int S_SPARSE = 4096;
constexpr int NSPLIT   = 64;                 // lane split of S per query
constexpr int Q        = 8;                  // queries per thread
constexpr int THREADS  = 512;                // 8 waves
constexpr int PPB      = 64;                 // queries per block (8 waves x 8)
constexpr int NITER    = S_SPARSE / NSPLIT;  // 64 scan iters per lane
constexpr int K        = 3;                  // per-split top-K kept
constexpr int KA       = 5;                  // stage-A top-K per 24-key chunk
constexpr int KM       = 8;                  // final candidates for f64 re-rank
constexpr int KROW     = NSPLIT * K + 8;     // 200 dwords
constexpr int KBUF2_OFF_DW = PPB * KROW;     // 12800 dwords
constexpr int PQ_PAD   = 64;                 // prefetch overrun guard

__device__ __forceinline__ unsigned med3u(unsigned a, unsigned b, unsigned c) {
    unsigned d;
    asm("v_med3_u32 %0, %1, %2, %3" : "=v"(d) : "v"(a), "v"(b), "v"(c));
    return d;
}

__global__ __launch_bounds__(THREADS, 4)
void upsample_knn3(const float* __restrict__ xyz,
                   const float* __restrict__ sxyz,
                   const float* __restrict__ sflow,
                   float* __restrict__ out,
                   int N)
{
    // 65 KiB: AoS float4 sparse points during scan; aliased as key-exchange
    // buffers afterwards (epilogue re-reads coords from global/L2).
    __shared__ __align__(16) unsigned char smem_raw[(S_SPARSE + PQ_PAD) * 16];
    float4*   pq   = reinterpret_cast<float4*>(smem_raw);
    unsigned* kbuf = reinterpret_cast<unsigned*>(smem_raw);

    const int t   = threadIdx.x;
    const int s   = t & 63;                  // lane = split
    const int g   = t >> 6;                  // wave = query group 0..7
    const int b   = blockIdx.y;
    const int chk = blockIdx.x;              // 0..255

    // ---- stage sparse points as AoS {x,y,z,|p|^2} ----
    const float* sx = sxyz + (size_t)b * 3 * S_SPARSE;
    const float* sy = sx + S_SPARSE;
    const float* sz = sy + S_SPARSE;
    #pragma unroll
    for (int it = 0; it < S_SPARSE / (THREADS * 4); ++it) {      // 2 iters
        const int j0 = (t + it * THREADS) * 4;
        const float4 vx = *reinterpret_cast<const float4*>(sx + j0);
        const float4 vy = *reinterpret_cast<const float4*>(sy + j0);
        const float4 vz = *reinterpret_cast<const float4*>(sz + j0);
        #pragma unroll
        for (int e = 0; e < 4; ++e) {
            const float px = (&vx.x)[e], py = (&vy.x)[e], pz = (&vz.x)[e];
            const float pp = fmaf(pz, pz, fmaf(py, py, px * px));
            pq[j0 + e] = make_float4(px, py, pz, pp);
        }
    }

    // ---- my 8 query points: precompute -2q and qq + bias ----
    const float* xb = xyz + (size_t)b * 3 * N;
    const int p0 = chk * PPB + g * Q;
    float m2x[Q], m2y[Q], m2z[Q], qqc[Q];
    {
        const float4 x0 = *reinterpret_cast<const float4*>(xb + p0);
        const float4 x1 = *reinterpret_cast<const float4*>(xb + p0 + 4);
        const float4 y0 = *reinterpret_cast<const float4*>(xb + N + p0);
        const float4 y1 = *reinterpret_cast<const float4*>(xb + N + p0 + 4);
        const float4 z0 = *reinterpret_cast<const float4*>(xb + 2 * N + p0);
        const float4 z1 = *reinterpret_cast<const float4*>(xb + 2 * N + p0 + 4);
        #pragma unroll
        for (int q = 0; q < Q; ++q) {
            const float qx = (q < 4) ? (&x0.x)[q] : (&x1.x)[q - 4];
            const float qy = (q < 4) ? (&y0.x)[q] : (&y1.x)[q - 4];
            const float qz = (q < 4) ? (&z0.x)[q] : (&z1.x)[q - 4];
            m2x[q] = -2.0f * qx;
            m2y[q] = -2.0f * qy;
            m2z[q] = -2.0f * qz;
            qqc[q] = fmaf(qz, qz, fmaf(qy, qy, qx * qx)) + 1e-3f;
        }
    }
    __syncthreads();

    // ---- scan: 1 ds_read_b128/point, 8 ops/pair, top-3 med3 insert ----
    unsigned k0[Q], k1[Q], k2[Q];
    #pragma unroll
    for (int q = 0; q < Q; ++q) { k0[q]=0xFFFFFFFFu; k1[q]=0xFFFFFFFFu; k2[q]=0xFFFFFFFFu; }

    float4 cur = pq[s];
    #pragma unroll 2
    for (int i = 0; i < NITER; ++i) {
        const int j = (i << 6) | s;
        const float4 nxt = pq[j + 64];       // last-iter prefetch lands in pad
        #pragma unroll
        for (int q = 0; q < Q; ++q) {
            const float v  = fmaf(m2x[q], cur.x,
                             fmaf(m2y[q], cur.y,
                             fmaf(m2z[q], cur.z, qqc[q])));
            const float v2 = v + cur.w;      // = d2 + 1e-3 (+-5e-6), > 0
            const unsigned c = (__float_as_uint(v2) & 0xFFFFF000u) | (unsigned)j;
            k2[q] = med3u(k1[q], k2[q], c);
            k1[q] = med3u(k0[q], k1[q], c);
            k0[q] = min(k0[q], c);
        }
        cur = nxt;
    }

    // ---- publish per-split sorted-3 lists (alias over pq) ----
    __syncthreads();
    #pragma unroll
    for (int q = 0; q < Q; ++q) {
        const int base = (g * Q + q) * KROW + s * K;
        kbuf[base + 0] = k0[q];
        kbuf[base + 1] = k1[q];
        kbuf[base + 2] = k2[q];
    }
    __syncthreads();

    // ---- merge stage A: 8 threads/query, each folds 24 keys -> top-5 ----
    {
        const int lp = t >> 3;               // local query 0..63
        const int ch = t & 7;                // chunk 0..7
        unsigned m0=0xFFFFFFFFu, m1=0xFFFFFFFFu, m2=0xFFFFFFFFu,
                 m3=0xFFFFFFFFu, m4=0xFFFFFFFFu;
        const unsigned* rowp = kbuf + lp * KROW + ch * 24;
        #pragma unroll
        for (int c = 0; c < 24; ++c) {
            const unsigned cc = rowp[c];
            m4 = med3u(m3, m4, cc);
            m3 = med3u(m2, m3, cc);
            m2 = med3u(m1, m2, cc);
            m1 = med3u(m0, m1, cc);
            m0 = min(m0, cc);
        }
        unsigned* o = kbuf + KBUF2_OFF_DW + (lp * 8 + ch) * KA;
        o[0]=m0; o[1]=m1; o[2]=m2; o[3]=m3; o[4]=m4;
    }
    __syncthreads();

    // ---- merge stage B + exact-f64 re-rank + f64 IDW (t < 64) ----
    if (t < PPB) {
        unsigned bk[KM];
        #pragma unroll
        for (int k = 0; k < KM; ++k) bk[k] = 0xFFFFFFFFu;
        const unsigned* inp = kbuf + KBUF2_OFF_DW + t * 8 * KA;
        #pragma unroll
        for (int c = 0; c < 8 * KA; ++c) {
            const unsigned cc = inp[c];
            bk[7] = med3u(bk[6], bk[7], cc);
            bk[6] = med3u(bk[5], bk[6], cc);
            bk[5] = med3u(bk[4], bk[5], cc);
            bk[4] = med3u(bk[3], bk[4], cc);
            bk[3] = med3u(bk[2], bk[3], cc);
            bk[2] = med3u(bk[1], bk[2], cc);
            bk[1] = med3u(bk[0], bk[1], cc);
            bk[0] = min(bk[0], cc);
        }

        // exact-f64 re-rank of 8 candidates (identical to rounds 1-4)
        const int pt = chk * PPB + t;
        const double qxd = (double)xb[pt];
        const double qyd = (double)xb[N + pt];
        const double qzd = (double)xb[2 * N + pt];

        double e0 = 1e300, e1 = 1e300, e2 = 1e300;
        int    j0 = 0,     j1 = 0,     j2 = 0;
        #pragma unroll
        for (int c = 0; c < KM; ++c) {
            const int    j  = (int)(bk[c] & 0xFFFu);
            const double dx = qxd - (double)sx[j];
            const double dy = qyd - (double)sy[j];
            const double dz = qzd - (double)sz[j];
            const double d2 = dx * dx + dy * dy + dz * dz;
            if (d2 < e2) {
                if (d2 < e1) {
                    e2 = e1; j2 = j1;
                    if (d2 < e0) { e1 = e0; j1 = j0; e0 = d2; j0 = j; }
                    else         { e1 = d2; j1 = j; }
                } else {
                    e2 = d2; j2 = j;
                }
            }
        }

        double dist0 = sqrt(e0); dist0 = dist0 > 1e-10 ? dist0 : 1e-10;
        double dist1 = sqrt(e1); dist1 = dist1 > 1e-10 ? dist1 : 1e-10;
        double dist2 = sqrt(e2); dist2 = dist2 > 1e-10 ? dist2 : 1e-10;
        const double inv0 = 1.0 / dist0;
        const double inv1 = 1.0 / dist1;
        const double inv2 = 1.0 / dist2;
        const double wsum = inv0 + inv1 + inv2;

        const float* fb = sflow + (size_t)b * 3 * S_SPARSE;
        float*       ob = out   + (size_t)b * 3 * N;
        #pragma unroll
        for (int c = 0; c < 3; ++c) {
            const float* fc = fb + c * S_SPARSE;
            const double o =
                (inv0 * (double)fc[j0] +
                 inv1 * (double)fc[j1] +
                 inv2 * (double)fc[j2]) / wsum;
            ob[c * N + pt] = (float)o;
        }
    }
}

extern "C" void kernel_launch(void* const* d_in, const int* in_sizes, int n_in,
                              void* d_out, int out_size, void* d_ws, size_t ws_size,
                              hipStream_t stream)
{
    const float* xyz  = (const float*)d_in[0];
    const float* sxyz = (const float*)d_in[1];
    const float* sflw = (const float*)d_in[2];
    float*       out  = (float*)d_out;

    const int B = 2;
    const int N = in_sizes[0] / (3 * B);     // 16384

    dim3 grid(N / PPB, B);                   // 256 x 2 = 512 blocks, 2/CU
    upsample_knn3<<<grid, THREADS, 0, stream>>>(xyz, sxyz, sflw, out, N);
}